// Round 13
// baseline (88.618 us; speedup 1.0000x reference)
//
#include <hip/hip_runtime.h>
#include <math.h>

#define L_C 1024
#define B_C 32
#define F_C 24
#define S_C 12
#define N_C (L_C*B_C)   // 32768
#define DWIN 20

// ---------------------------------------------------------------------------
// Kernel A: windowed Gaussian message passing, F and S in one launch.
// ---------------------------------------------------------------------------
__global__ void msg_all(const float* __restrict__ f, const float* __restrict__ s,
                        float* __restrict__ fmp, float* __restrict__ fmf,
                        float* __restrict__ smp, float* __restrict__ smf) {
    int idx = blockIdx.x * 256 + threadIdx.x;
    const float* x; float *mp, *mf; int stride, i;
    if (idx < N_C * F_C) { x = f; mp = fmp; mf = fmf; stride = B_C*F_C; i = idx; }
    else { x = s; mp = smp; mf = smf; stride = B_C*S_C; i = idx - N_C*F_C; }
    int t = i / stride;
    float accp = 0.f, accf = 0.f;
    #pragma unroll
    for (int d = 1; d <= DWIN; ++d) {
        float w = expf(-0.125f * (float)(d * d));
        if (t >= d)      accp += w * x[i - d * stride];
        if (t + d < L_C) accf += w * x[i + d * stride];
    }
    mp[i] = accp / fmaxf((float)t, 1.0f);
    mf[i] = accf / fmaxf((float)(L_C - 1 - t), 1.0f);
}

__device__ inline float segred_max(float v) {
    #pragma unroll
    for (int o = 16; o >= 1; o >>= 1) v = fmaxf(v, __shfl_xor(v, o, 32));
    return v;
}
__device__ inline float segred_sum(float v) {
    #pragma unroll
    for (int o = 16; o >= 1; o >>= 1) v += __shfl_xor(v, o, 32);
    return v;
}

// ---------------------------------------------------------------------------
// Kernel B v13: TWO n per wave, counted-vmcnt pipelined, zero barriers.
// Wave w of block b owns nu0 = (b*2+w)*2 and nu1 = nu0+1 (adjacent -> L2
// locality). Straight-line schedule (no loops, no pointer arrays):
//   fvalA/fvalB per-lane loads            (vmem, oldest)
//   STAGE A -> slice0 (7x global_load_lds)
//   STAGE B -> slice1 (7x global_load_lds, newest 7)
//   s_waitcnt vmcnt(7)   [fvals + A landed; B still in flight]
//   dots A (LDS slice0 + SMEM vectors)    <- hides B latency
//   s_waitcnt vmcnt(0)   [B landed]
//   dots B (LDS slice1)
//   tails A+B (softmax x2 each, 5 loss terms, stores)  <- pure VALU, free
// LDS: 2 waves x 12672 B = 25344 B/block -> 6 blocks/CU = 12 waves/CU.
// Slice float layout: ff@0(576) fs@576(288) fst@864(288) sft@1152(288) ss@1440(144)
// ---------------------------------------------------------------------------
__global__ __launch_bounds__(128, 3) void fuse_kernel(
    const float* __restrict__ f,  const float* __restrict__ s,
    const float* __restrict__ fs, const float* __restrict__ ff,
    const float* __restrict__ ss, const float* __restrict__ fst,
    const float* __restrict__ sft,
    const int* __restrict__ fl, const int* __restrict__ sl,
    const int* __restrict__ yl, const int* __restrict__ y2f,
    const int* __restrict__ y2s,
    const float* __restrict__ fmp, const float* __restrict__ fmf,
    const float* __restrict__ smp, const float* __restrict__ smf,
    float* __restrict__ outf, float* __restrict__ outs,
    float* __restrict__ part)
{
    __shared__ float4 L4[2*792];    // 25344 B (2 waves x 2 slices x 6336 B)
    const int tid  = threadIdx.x;
    const int w    = tid >> 6;
    const int lane = tid & 63;
    char* LBw = (char*)L4 + w*12672;

    const int nu0 = __builtin_amdgcn_readfirstlane((blockIdx.x*2 + w)*2);
    const int nu1 = nu0 + 1;

    const bool isF    = lane < 32;
    const bool active = (lane < 24) | (lane >= 32 && lane < 44);
    const int gg = (lane < 24) ? lane : 23;
    const int tt = ((lane & 31) < 12) ? (lane & 31) : 11;

    // ---- per-lane original logits FIRST (oldest vmem ops) ----
    float fvalA = 0.f, fvalB = 0.f;
    if (lane < 24) {
        fvalA = f[(size_t)nu0*24 + lane];
        fvalB = f[(size_t)nu1*24 + lane];
    } else if (lane >= 32 && lane < 44) {
        fvalA = s[(size_t)nu0*12 + (lane - 32)];
        fvalB = s[(size_t)nu1*12 + (lane - 32)];
    }

    // ---- stage both slices: 7 coalesced global_load_lds each ----
    // per-n f4 stream: [0,144) ff | [144,216) fs | [216,288) fst |
    //                  [288,360) sft | [360,396) ss
    {
        auto src = [&](int nu, int j) -> const char* {
            int i = 64*j + lane; if (i > 395) i = 395;
            const float* base; int off, af4;
            if (i < 144)      { base = ff;  off = i;       af4 = 144; }
            else if (i < 216) { base = fs;  off = i - 144; af4 = 72;  }
            else if (i < 288) { base = fst; off = i - 216; af4 = 72;  }
            else if (i < 360) { base = sft; off = i - 288; af4 = 72;  }
            else              { base = ss;  off = i - 360; af4 = 36;  }
            return (const char*)base + ((size_t)nu*af4 + off)*16;
        };
        #define ISSUE(NU, SL, J) \
            __builtin_amdgcn_global_load_lds( \
                (const __attribute__((address_space(1))) void*)(src(NU, J)), \
                (__attribute__((address_space(3))) void*)(LBw + (SL)*6336 + (J)*1024), \
                16, 0, 0)
        ISSUE(nu0,0,0); ISSUE(nu0,0,1); ISSUE(nu0,0,2);
        ISSUE(nu0,0,3); ISSUE(nu0,0,4); ISSUE(nu0,0,5);
        if (lane < 12) { ISSUE(nu0,0,6); }
        ISSUE(nu1,1,0); ISSUE(nu1,1,1); ISSUE(nu1,1,2);
        ISSUE(nu1,1,3); ISSUE(nu1,1,4); ISSUE(nu1,1,5);
        if (lane < 12) { ISSUE(nu1,1,6); }
        #undef ISSUE
    }

    // ---- the five dot phases for one slice (verified R11 code) ----
    auto dots = [&](const float* B, int nu) -> float {
        const float* vmpf = fmp + (size_t)nu*24;   // SMEM scalar loads
        const float* vmff = fmf + (size_t)nu*24;
        const float* vmps = smp + (size_t)nu*12;
        const float* vmfs = smf + (size_t)nu*12;
        const float* vF   = f   + (size_t)nu*24;
        const float* vS   = s   + (size_t)nu*12;

        float acc0 = 0.f, acc1 = 0.f, acc2 = 0.f, acc3 = 0.f;
        // P1: vmpf . {ff[:,g] | fst[:,t]}   (b32 cols)
        {
            const float* p = isF ? (B + gg) : (B + 864 + tt);
            const int st   = isF ? 24 : 12;
            #pragma unroll
            for (int k = 0; k < 24; ++k) acc0 += vmpf[k] * p[k*st];
        }
        // P2: {ff[g,:] | sft[t,:]} . vmff   (b128 rows)
        {
            const float4* r = (const float4*)(B + (isF ? gg*24 : 1152 + tt*24));
            #pragma unroll
            for (int j = 0; j < 6; ++j) {
                float4 a = r[j];
                acc1 += a.x*vmff[4*j] + a.y*vmff[4*j+1] + a.z*vmff[4*j+2] + a.w*vmff[4*j+3];
            }
        }
        // P3: vmps . {sft[:,g] | ss[:,t]}   (b32 cols)
        {
            const float* p = isF ? (B + 1152 + gg) : (B + 1440 + tt);
            const int st   = isF ? 24 : 12;
            #pragma unroll
            for (int k = 0; k < 12; ++k) acc2 += vmps[k] * p[k*st];
        }
        // P4: {fst[g,:] | ss[t,:]} . vmfs   (b128 rows)
        {
            const float4* r = (const float4*)(B + (isF ? 864 + gg*12 : 1440 + tt*12));
            #pragma unroll
            for (int j = 0; j < 3; ++j) {
                float4 a = r[j];
                acc3 += a.x*vmfs[4*j] + a.y*vmfs[4*j+1] + a.z*vmfs[4*j+2] + a.w*vmfs[4*j+3];
            }
        }
        // P5: f: fs[g,:] . s (b128 rows) | s: f . fs[:,t] (b32 cols)
        if (isF) {
            const float4* r = (const float4*)(B + 576 + gg*12);
            #pragma unroll
            for (int j = 0; j < 3; ++j) {
                float4 a = r[j];
                acc2 += a.x*vS[4*j] + a.y*vS[4*j+1] + a.z*vS[4*j+2] + a.w*vS[4*j+3];
            }
        } else {
            const float* p = B + 576 + tt;
            #pragma unroll
            for (int k = 0; k < 24; ++k) acc3 += vF[k] * p[k*12];
        }
        return (acc0 + acc1) + (acc2 + acc3);
    };

    // ---- tail: softmax(orig)+softmax(next)+5 loss terms (verified R11) ----
    auto tail = [&](int nu, float fval, float acc) {
        float nx = fval + 0.5f * acc;
        float xo = active ? fval : -INFINITY;
        float xn = active ? nx   : -INFINITY;

        float mo = segred_max(xo);
        float eo = expf(xo - mo);
        float so = segred_sum(eo);
        float lse_o = mo + logf(so);

        float mn = segred_max(xn);
        float en = expf(xn - mn);
        float sn = segred_sum(en);
        float pr = en / sn;
        float lse_n = mn + logf(sn);

        const size_t nn = (size_t)nu;
        if (lane < 24)                    outf[nn*24 + lane]        = pr;
        else if (lane >= 32 && lane < 44) outs[nn*12 + (lane - 32)] = pr;

        const int fln = fl[nu], sln = sl[nu], yln = yl[nu];
        const int yfi = y2f[yln], ysi = y2s[yln];
        float lse_o_s = __shfl(lse_o, 32, 64);
        float lse_n_s = __shfl(lse_n, 32, 64);
        float vf_fl   = __shfl(xo, fln, 64);
        float vs_sl   = __shfl(xo, 32 + sln, 64);
        float nf_fl   = __shfl(xn, fln, 64);
        float ns_sl   = __shfl(xn, 32 + sln, 64);
        float vf_y    = __shfl(xo, yfi, 64);
        float vs_y    = __shfl(xo, 32 + ysi, 64);
        if (lane == 0) {
            float ce1 = lse_o   - vf_fl;
            float ce2 = lse_o_s - vs_sl;
            float stc = -expf(vf_y - lse_o) * expf(vs_y - lse_o_s);
            float ce3 = lse_n   - nf_fl;
            float ce4 = lse_n_s - ns_sl;
            part[nu] = ce1 + ce2 + stc + ce3 + ce4;
        }
    };

    // A (+fvals) landed; B's 7 loads (the newest) may remain in flight
    asm volatile("s_waitcnt vmcnt(7)" ::: "memory");
    __builtin_amdgcn_sched_barrier(0);
    float accA = dots((const float*)LBw, nu0);

    // B landed
    asm volatile("s_waitcnt vmcnt(0)" ::: "memory");
    __builtin_amdgcn_sched_barrier(0);
    float accB = dots((const float*)(LBw + 6336), nu1);

    // tails: pure VALU/shuffle, independent chains interleave
    tail(nu0, fvalA, accA);
    tail(nu1, fvalB, accB);
}

// ---------------------------------------------------------------------------
// Kernel C: deterministic fixed-order loss reduction (1024 thr, f4 loads).
// ---------------------------------------------------------------------------
__global__ __launch_bounds__(1024) void loss_reduce(const float* __restrict__ part,
                                                    float* __restrict__ out) {
    __shared__ float sm[1024];
    float a = 0.f;
    const float4* p4 = (const float4*)part;
    for (int i = threadIdx.x; i < N_C/4; i += 1024) {
        float4 v = p4[i];
        a += (v.x + v.y) + (v.z + v.w);
    }
    sm[threadIdx.x] = a;
    __syncthreads();
    for (int o = 512; o >= 1; o >>= 1) {
        if ((int)threadIdx.x < o) sm[threadIdx.x] += sm[threadIdx.x + o];
        __syncthreads();
    }
    if (threadIdx.x == 0) out[0] = sm[0] * (1.0f / (float)N_C);
}

extern "C" void kernel_launch(void* const* d_in, const int* in_sizes, int n_in,
                              void* d_out, int out_size, void* d_ws, size_t ws_size,
                              hipStream_t stream) {
    (void)in_sizes; (void)n_in; (void)out_size; (void)ws_size;

    const float* f   = (const float*)d_in[0];
    const float* s   = (const float*)d_in[1];
    const float* fs  = (const float*)d_in[2];
    const float* ff  = (const float*)d_in[3];
    const float* ss  = (const float*)d_in[4];
    const float* fst = (const float*)d_in[5];
    const float* sft = (const float*)d_in[6];
    const int* fl  = (const int*)d_in[7];
    const int* sl  = (const int*)d_in[8];
    const int* yl  = (const int*)d_in[9];
    const int* y2f = (const int*)d_in[11];
    const int* y2s = (const int*)d_in[12];

    float* ws   = (float*)d_ws;
    float* fmp  = ws;
    float* fmf  = fmp + (size_t)N_C * F_C;
    float* smp  = fmf + (size_t)N_C * F_C;
    float* smf  = smp + (size_t)N_C * S_C;
    float* part = smf + (size_t)N_C * S_C;   // N_C floats

    float* outf = (float*)d_out;
    float* outs = outf + (size_t)N_C * F_C;
    float* outl = outs + (size_t)N_C * S_C;

    msg_all<<<(N_C * (F_C + S_C)) / 256, 256, 0, stream>>>(f, s, fmp, fmf, smp, smf);
    fuse_kernel<<<N_C / 4, 128, 0, stream>>>(f, s, fs, ff, ss, fst, sft,
                                             fl, sl, yl, y2f, y2s,
                                             fmp, fmf, smp, smf,
                                             outf, outs, part);
    loss_reduce<<<1, 1024, 0, stream>>>(part, outl);
}

// Round 14
// 72.733 us; speedup vs baseline: 1.2184x; 1.2184x over previous
//
#include <hip/hip_runtime.h>
#include <math.h>

#define L_C 1024
#define B_C 32
#define F_C 24
#define S_C 12
#define N_C (L_C*B_C)   // 32768
#define DWIN 20

// ---------------------------------------------------------------------------
// Kernel A: windowed Gaussian message passing, F and S in one launch.
// ---------------------------------------------------------------------------
__global__ void msg_all(const float* __restrict__ f, const float* __restrict__ s,
                        float* __restrict__ fmp, float* __restrict__ fmf,
                        float* __restrict__ smp, float* __restrict__ smf) {
    int idx = blockIdx.x * 256 + threadIdx.x;
    const float* x; float *mp, *mf; int stride, i;
    if (idx < N_C * F_C) { x = f; mp = fmp; mf = fmf; stride = B_C*F_C; i = idx; }
    else { x = s; mp = smp; mf = smf; stride = B_C*S_C; i = idx - N_C*F_C; }
    int t = i / stride;
    float accp = 0.f, accf = 0.f;
    #pragma unroll
    for (int d = 1; d <= DWIN; ++d) {
        float w = expf(-0.125f * (float)(d * d));
        if (t >= d)      accp += w * x[i - d * stride];
        if (t + d < L_C) accf += w * x[i + d * stride];
    }
    mp[i] = accp / fmaxf((float)t, 1.0f);
    mf[i] = accf / fmaxf((float)(L_C - 1 - t), 1.0f);
}

__device__ inline float segred_max(float v) {
    #pragma unroll
    for (int o = 16; o >= 1; o >>= 1) v = fmaxf(v, __shfl_xor(v, o, 32));
    return v;
}
__device__ inline float segred_sum(float v) {
    #pragma unroll
    for (int o = 16; o >= 1; o >>= 1) v += __shfl_xor(v, o, 32);
    return v;
}

// ---------------------------------------------------------------------------
// Kernel B v14: R11 (best, 73.7us) + XCD-CONTIGUOUS block swizzle ONLY.
// Blocks dispatch round-robin over 8 XCDs; wb = (bid%8)*1024 + bid/8 makes
// XCD x process n in [x*4096, (x+1)*4096): five dense sequential streams
// per XCD (DRAM row-buffer locality) instead of 2-9KB chunks at 18-72KB
// strides. Bijective (8192 % 8 == 0). Everything else byte-identical to R11.
// ---------------------------------------------------------------------------
__global__ __launch_bounds__(256, 6) void fuse_kernel(
    const float* __restrict__ f,  const float* __restrict__ s,
    const float* __restrict__ fs, const float* __restrict__ ff,
    const float* __restrict__ ss, const float* __restrict__ fst,
    const float* __restrict__ sft,
    const int* __restrict__ fl, const int* __restrict__ sl,
    const int* __restrict__ yl, const int* __restrict__ y2f,
    const int* __restrict__ y2s,
    const float* __restrict__ fmp, const float* __restrict__ fmf,
    const float* __restrict__ smp, const float* __restrict__ smf,
    float* __restrict__ outf, float* __restrict__ outs,
    float* __restrict__ part)
{
    __shared__ float4 L4[4*396];    // 25344 B
    const int tid  = threadIdx.x;
    const int w    = tid >> 6;
    const int lane = tid & 63;
    char* LBw = (char*)L4 + w*6336;

    // XCD-contiguous swizzle: XCD (bid%8) gets the contiguous work range
    const int wb = (blockIdx.x & 7) * 1024 + (blockIdx.x >> 3);
    const int nu = __builtin_amdgcn_readfirstlane(wb*4 + w);

    // ---- stage this wave's slice: 7 coalesced global_load_lds ----
    // per-n f4 stream: [0,144) ff | [144,216) fs | [216,288) fst |
    //                  [288,360) sft | [360,396) ss
    {
        auto src = [&](int j) -> const char* {
            int i = 64*j + lane; if (i > 395) i = 395;
            const float* base; int off, af4;
            if (i < 144)      { base = ff;  off = i;       af4 = 144; }
            else if (i < 216) { base = fs;  off = i - 144; af4 = 72;  }
            else if (i < 288) { base = fst; off = i - 216; af4 = 72;  }
            else if (i < 360) { base = sft; off = i - 288; af4 = 72;  }
            else              { base = ss;  off = i - 360; af4 = 36;  }
            return (const char*)base + ((size_t)nu*af4 + off)*16;
        };
        #define ISSUE(J) \
            __builtin_amdgcn_global_load_lds( \
                (const __attribute__((address_space(1))) void*)(src(J)), \
                (__attribute__((address_space(3))) void*)(LBw + (J)*1024), \
                16, 0, 0)
        ISSUE(0); ISSUE(1); ISSUE(2); ISSUE(3); ISSUE(4); ISSUE(5);
        if (lane < 12) { ISSUE(6); }
        #undef ISSUE
    }

    const bool isF    = lane < 32;
    const bool active = (lane < 24) | (lane >= 32 && lane < 44);
    const int gg = (lane < 24) ? lane : 23;
    const int tt = ((lane & 31) < 12) ? (lane & 31) : 11;

    // wave-uniform vectors -> scalar (SMEM) loads (overlap staging latency)
    const float* vmpf = fmp + (size_t)nu*24;
    const float* vmff = fmf + (size_t)nu*24;
    const float* vmps = smp + (size_t)nu*12;
    const float* vmfs = smf + (size_t)nu*12;
    const float* vF   = f   + (size_t)nu*24;
    const float* vS   = s   + (size_t)nu*12;

    // per-lane original logit (independent global load, also overlaps)
    float fval = 0.f;
    if (lane < 24)                    fval = vF[lane];
    else if (lane >= 32 && lane < 44) fval = vS[lane - 32];

    const int fln = fl[nu], sln = sl[nu], yln = yl[nu];
    const int yfi = y2f[yln], ysi = y2s[yln];

    // wave's own staging landed (no barrier: slice is wave-private)
    asm volatile("s_waitcnt vmcnt(0)" ::: "memory");
    __builtin_amdgcn_sched_barrier(0);

    const float* B = (const float*)LBw;
    float acc0 = 0.f, acc1 = 0.f, acc2 = 0.f, acc3 = 0.f;

    // P1: vmpf . {ff[:,g] | fst[:,t]}   (b32 cols, lanes consecutive)
    {
        const float* p = isF ? (B + gg) : (B + 864 + tt);
        const int st   = isF ? 24 : 12;
        #pragma unroll
        for (int k = 0; k < 24; ++k) acc0 += vmpf[k] * p[k*st];
    }
    // P2: {ff[g,:] | sft[t,:]} . vmff   (b128 rows)
    {
        const float4* r = (const float4*)(B + (isF ? gg*24 : 1152 + tt*24));
        #pragma unroll
        for (int j = 0; j < 6; ++j) {
            float4 a = r[j];
            acc1 += a.x*vmff[4*j] + a.y*vmff[4*j+1] + a.z*vmff[4*j+2] + a.w*vmff[4*j+3];
        }
    }
    // P3: vmps . {sft[:,g] | ss[:,t]}   (b32 cols)
    {
        const float* p = isF ? (B + 1152 + gg) : (B + 1440 + tt);
        const int st   = isF ? 24 : 12;
        #pragma unroll
        for (int k = 0; k < 12; ++k) acc2 += vmps[k] * p[k*st];
    }
    // P4: {fst[g,:] | ss[t,:]} . vmfs   (b128 rows)
    {
        const float4* r = (const float4*)(B + (isF ? 864 + gg*12 : 1440 + tt*12));
        #pragma unroll
        for (int j = 0; j < 3; ++j) {
            float4 a = r[j];
            acc3 += a.x*vmfs[4*j] + a.y*vmfs[4*j+1] + a.z*vmfs[4*j+2] + a.w*vmfs[4*j+3];
        }
    }
    // P5: f: fs[g,:] . s (b128 rows) | s: f . fs[:,t] (b32 cols)
    if (isF) {
        const float4* r = (const float4*)(B + 576 + gg*12);
        #pragma unroll
        for (int j = 0; j < 3; ++j) {
            float4 a = r[j];
            acc2 += a.x*vS[4*j] + a.y*vS[4*j+1] + a.z*vS[4*j+2] + a.w*vS[4*j+3];
        }
    } else {
        const float* p = B + 576 + tt;
        #pragma unroll
        for (int k = 0; k < 24; ++k) acc3 += vF[k] * p[k*12];
    }

    float nx = fval + 0.5f * ((acc0 + acc1) + (acc2 + acc3));
    float xo = active ? fval : -INFINITY;
    float xn = active ? nx   : -INFINITY;

    // softmax/LSE of original + next logits
    float mo = segred_max(xo);
    float eo = expf(xo - mo);
    float so = segred_sum(eo);
    float lse_o = mo + logf(so);

    float mn = segred_max(xn);
    float en = expf(xn - mn);
    float sn = segred_sum(en);
    float pr = en / sn;
    float lse_n = mn + logf(sn);

    const size_t nn = (size_t)nu;
    if (lane < 24)                    outf[nn*24 + lane]        = pr;
    else if (lane >= 32 && lane < 44) outs[nn*12 + (lane - 32)] = pr;

    float lse_o_s = __shfl(lse_o, 32, 64);
    float lse_n_s = __shfl(lse_n, 32, 64);
    float vf_fl   = __shfl(xo, fln, 64);
    float vs_sl   = __shfl(xo, 32 + sln, 64);
    float nf_fl   = __shfl(xn, fln, 64);
    float ns_sl   = __shfl(xn, 32 + sln, 64);
    float vf_y    = __shfl(xo, yfi, 64);
    float vs_y    = __shfl(xo, 32 + ysi, 64);
    if (lane == 0) {
        float ce1 = lse_o   - vf_fl;
        float ce2 = lse_o_s - vs_sl;
        float stc = -expf(vf_y - lse_o) * expf(vs_y - lse_o_s);
        float ce3 = lse_n   - nf_fl;
        float ce4 = lse_n_s - ns_sl;
        part[nu] = ce1 + ce2 + stc + ce3 + ce4;
    }
}

// ---------------------------------------------------------------------------
// Kernel C: deterministic fixed-order loss reduction (1024 thr, f4 loads).
// ---------------------------------------------------------------------------
__global__ __launch_bounds__(1024) void loss_reduce(const float* __restrict__ part,
                                                    float* __restrict__ out) {
    __shared__ float sm[1024];
    float a = 0.f;
    const float4* p4 = (const float4*)part;
    for (int i = threadIdx.x; i < N_C/4; i += 1024) {
        float4 v = p4[i];
        a += (v.x + v.y) + (v.z + v.w);
    }
    sm[threadIdx.x] = a;
    __syncthreads();
    for (int o = 512; o >= 1; o >>= 1) {
        if ((int)threadIdx.x < o) sm[threadIdx.x] += sm[threadIdx.x + o];
        __syncthreads();
    }
    if (threadIdx.x == 0) out[0] = sm[0] * (1.0f / (float)N_C);
}

extern "C" void kernel_launch(void* const* d_in, const int* in_sizes, int n_in,
                              void* d_out, int out_size, void* d_ws, size_t ws_size,
                              hipStream_t stream) {
    (void)in_sizes; (void)n_in; (void)out_size; (void)ws_size;

    const float* f   = (const float*)d_in[0];
    const float* s   = (const float*)d_in[1];
    const float* fs  = (const float*)d_in[2];
    const float* ff  = (const float*)d_in[3];
    const float* ss  = (const float*)d_in[4];
    const float* fst = (const float*)d_in[5];
    const float* sft = (const float*)d_in[6];
    const int* fl  = (const int*)d_in[7];
    const int* sl  = (const int*)d_in[8];
    const int* yl  = (const int*)d_in[9];
    const int* y2f = (const int*)d_in[11];
    const int* y2s = (const int*)d_in[12];

    float* ws   = (float*)d_ws;
    float* fmp  = ws;
    float* fmf  = fmp + (size_t)N_C * F_C;
    float* smp  = fmf + (size_t)N_C * F_C;
    float* smf  = smp + (size_t)N_C * S_C;
    float* part = smf + (size_t)N_C * S_C;   // N_C floats

    float* outf = (float*)d_out;
    float* outs = outf + (size_t)N_C * F_C;
    float* outl = outs + (size_t)N_C * S_C;

    msg_all<<<(N_C * (F_C + S_C)) / 256, 256, 0, stream>>>(f, s, fmp, fmf, smp, smf);
    fuse_kernel<<<N_C / 4, 256, 0, stream>>>(f, s, fs, ff, ss, fst, sft,
                                             fl, sl, yl, y2f, y2s,
                                             fmp, fmf, smp, smf,
                                             outf, outs, part);
    loss_reduce<<<1, 1024, 0, stream>>>(part, outl);
}